// Round 5
// baseline (371.719 us; speedup 1.0000x reference)
//
#include <hip/hip_runtime.h>

#define T 512
constexpr int Bc = 512, Nc = 40, Hc = 128, FEc = 16, Mc = 128, OUTc = 128, NPASS = 3;
constexpr int ROWP = 136;    // bf16 LDS row pitch: 2-way bank alias on b128 A-frag reads (free)
constexpr int EPOOL = 1024;  // edge pool slots (mean ~296; fallback handles overflow)

typedef __attribute__((ext_vector_type(8))) short short8;
typedef __attribute__((ext_vector_type(4))) float floatx4;
typedef __attribute__((ext_vector_type(4))) float fvec4;

// ws layout (bf16 elements): fragment-major B operands
constexpr int WS_WN = 0, WS_WM = 16384, WS_WI = 32768, WS_WH = 81920, WS_WG = 131072, WS_WO = 163840;

__device__ __forceinline__ float fast_rcp(float x) { return __builtin_amdgcn_rcpf(x); }
__device__ __forceinline__ float fast_sigmoid(float x) { return fast_rcp(1.f + __expf(-x)); }
__device__ __forceinline__ float fast_tanh(float x) {
    float t = __expf(2.f * x);
    return 1.f - 2.f * fast_rcp(t + 1.f);
}
__device__ __forceinline__ float bf2f(unsigned short u) {
    union { unsigned int i; float f; } v; v.i = ((unsigned int)u) << 16; return v.f;
}
__device__ __forceinline__ unsigned short f2bf(float f) {
    union { float f; unsigned int i; } v; v.f = f;
    unsigned int r = v.i + 0x7fff + ((v.i >> 16) & 1);   // RNE
    return (unsigned short)(r >> 16);
}
__device__ __forceinline__ float bflo(unsigned int d) {
    union { unsigned int i; float f; } v; v.i = d << 16; return v.f;
}
__device__ __forceinline__ float bfhi(unsigned int d) {
    union { unsigned int i; float f; } v; v.i = d & 0xffff0000u; return v.f;
}

__device__ __forceinline__ floatx4 mm(short8 a, short8 b, floatx4 c) {
    return __builtin_amdgcn_mfma_f32_16x16x32_bf16(a, b, c, 0, 0, 0);
}
// A-fragment from LDS bf16 buffer: A[m=lane&15][k=quad*8+j]; rows>=40 clamped (their C rows discarded)
__device__ __forceinline__ short8 afrag(const unsigned short* buf, int mt, int kt, int lane) {
    int row = mt * 16 + (lane & 15); row = row > 39 ? 39 : row;
    return *(const short8*)(buf + row * ROWP + kt * 32 + (lane >> 4) * 8);
}
// B-fragment from global frag buffer (L2-resident)
__device__ __forceinline__ short8 bfrag(const unsigned short* w, int nt, int nKT, int kt, int lane) {
    return *(const short8*)(w + ((nt * nKT + kt) * 64 + lane) * 8);
}

// ---- prep: weights -> bf16 B-fragment layout in ws ----
__global__ void prep_kernel(const float* __restrict__ Wn, const float* __restrict__ Wm,
                            const float* __restrict__ Wi, const float* __restrict__ Wh,
                            const float* __restrict__ Wg, const float* __restrict__ Wo,
                            unsigned short* __restrict__ ws) {
    int c = blockIdx.x, lane = threadIdx.x;
    const float* W; int N, nKT, local; unsigned short* dst;
    if (c < 32)       { W = Wn; N = 128; nKT = 4; local = c;       dst = ws + WS_WN; }
    else if (c < 64)  { W = Wm; N = 128; nKT = 4; local = c - 32;  dst = ws + WS_WM; }
    else if (c < 160) { W = Wi; N = 384; nKT = 4; local = c - 64;  dst = ws + WS_WI; }
    else if (c < 256) { W = Wh; N = 384; nKT = 4; local = c - 160; dst = ws + WS_WH; }
    else if (c < 320) { W = Wg; N = 128; nKT = 8; local = c - 256; dst = ws + WS_WG; }
    else              { W = Wo; N = 128; nKT = 8; local = c - 320; dst = ws + WS_WO; }
    int nt = local / nKT, kt = local % nKT;
    int quad = lane >> 4, l16 = lane & 15;
    short8 v;
#pragma unroll
    for (int j = 0; j < 8; ++j) {
        int k = kt * 32 + quad * 8 + j;
        v[j] = (short)f2bf(W[k * N + nt * 16 + l16]);
    }
    *(short8*)(dst + local * 512 + lane * 8) = v;
}

// launch_bounds(T,2): cap 256 VGPR/wave. (T,4) capped arch regs at 64 and spilled
// ~450 MB/dispatch to scratch (R4: WRITE_SIZE 227 MB). Actual usage ~110-130 keeps
// 2 blocks/CU possible via LDS (78 KB) if <=128.
__global__ __launch_bounds__(T, 2) void mpnn_kernel(
    const float* __restrict__ nodes, const float* __restrict__ edges,
    const float* __restrict__ We, const float* __restrict__ bi,
    const float* __restrict__ bh, const float* __restrict__ bg,
    const float* __restrict__ bo, const unsigned short* __restrict__ ws,
    float* __restrict__ out)
{
    __shared__ __attribute__((aligned(16))) unsigned short s_hb[Nc * ROWP];   // bf16 h
    __shared__ __attribute__((aligned(16))) unsigned short s_mb[Nc * ROWP];   // bf16 messages / nodes(cat)
    __shared__ __attribute__((aligned(16))) unsigned short s_npb[Nc * ROWP];  // bf16 nghb_proj (init: slot_src tmp)
    __shared__ __attribute__((aligned(16))) unsigned short s_eb[Nc * ROWP];   // bf16 emb
    __shared__ __attribute__((aligned(16))) unsigned short s_pool[EPOOL * FEc]; // 32 KB compact edge features
    __shared__ unsigned char s_nbr[Nc][Nc];
    __shared__ int s_cnt[Nc];
    __shared__ int s_off[Nc];
    __shared__ int s_total;

    const int b = blockIdx.x, tid = threadIdx.x;
    const int lane = tid & 63, wave = tid >> 6;
    const int quad = lane >> 4, l16 = lane & 15;
    const int m = tid & 127, g = tid >> 7;   // attention mapping
    const int col = wave * 16 + l16;         // this thread's output column for all GEMMs

    const float* nodes_b = nodes + (size_t)b * Nc * Hc;
    const float* edges_b = edges + (size_t)b * Nc * Nc * FEc;
    const unsigned short* wWn = ws + WS_WN; const unsigned short* wWm = ws + WS_WM;
    const unsigned short* wWi = ws + WS_WI; const unsigned short* wWh = ws + WS_WH;
    const unsigned short* wWg = ws + WS_WG; const unsigned short* wWo = ws + WS_WO;

    // ---- init: fp32 h in registers (static (row,col)<->thread map), bf16 copy in LDS ----
    float hreg[3][4];
#pragma unroll
    for (int mt = 0; mt < 3; ++mt)
#pragma unroll
        for (int reg = 0; reg < 4; ++reg) {
            int row = mt * 16 + quad * 4 + reg;
            float v = (row < Nc) ? nodes_b[row * Hc + col] : 0.f;
            hreg[mt][reg] = v;
            if (row < Nc) s_hb[row * ROWP + col] = f2bf(v);
        }

    // ---- adjacency scan (streaming, non-temporal) ----
    for (int p = tid; p < Nc * Nc; p += T) {
        const fvec4* e4 = (const fvec4*)(edges_b + p * FEc);
        fvec4 a0 = __builtin_nontemporal_load(e4);
        fvec4 a1 = __builtin_nontemporal_load(e4 + 1);
        fvec4 a2 = __builtin_nontemporal_load(e4 + 2);
        fvec4 a3 = __builtin_nontemporal_load(e4 + 3);
        float s = a0.x + a0.y + a0.z + a0.w + a1.x + a1.y + a1.z + a1.w
                + a2.x + a2.y + a2.z + a2.w + a3.x + a3.y + a3.z + a3.w;
        ((unsigned char*)s_nbr)[p] = (s > 0.f) ? 1 : 0;
    }
    __syncthreads();
    if (tid < Nc) {               // compact neighbor list in place
        int c = 0;
#pragma unroll 1
        for (int j = 0; j < Nc; ++j)
            if (s_nbr[tid][j]) { s_nbr[tid][c] = (unsigned char)j; ++c; }
        s_cnt[tid] = c;
    }
    __syncthreads();
    if (tid == 0) {               // prefix-sum edge offsets
        int tot = 0;
#pragma unroll 1
        for (int i = 0; i < Nc; ++i) { s_off[i] = tot; tot += s_cnt[i]; }
        s_total = tot;
    }
    __syncthreads();
    int* slot_src = (int*)s_npb;  // temp alias; overwritten by Phase A of pass 0
    if (tid < Nc) {
        int base = s_off[tid], cnt = s_cnt[tid];
#pragma unroll 1
        for (int kn = 0; kn < cnt; ++kn) {
            int slot = base + kn;
            if (slot < EPOOL) slot_src[slot] = tid * Nc + s_nbr[tid][kn];
        }
    }
    __syncthreads();
    {   // fill compact bf16 edge pool
        int E = s_total < EPOOL ? s_total : EPOOL;
#pragma unroll 1
        for (int w = tid; w < E * 2; w += T) {
            int s = w >> 1, hf = w & 1;
            const float* src = edges_b + (size_t)slot_src[s] * FEc + hf * 8;
            fvec4 x = __builtin_nontemporal_load((const fvec4*)src);
            fvec4 y = __builtin_nontemporal_load((const fvec4*)(src + 4));
            short8 v;
            v[0] = (short)f2bf(x.x); v[1] = (short)f2bf(x.y); v[2] = (short)f2bf(x.z); v[3] = (short)f2bf(x.w);
            v[4] = (short)f2bf(y.x); v[5] = (short)f2bf(y.y); v[6] = (short)f2bf(y.z); v[7] = (short)f2bf(y.w);
            *(short8*)(s_pool + s * FEc + hf * 8) = v;
        }
    }
    __syncthreads();

    for (int pass = 0; pass < NPASS; ++pass) {
        // ---- Phase A: np = h@Wn, emb = h@Wm (B-frags in regs, reused across m-tiles) ----
#pragma unroll
        for (int jb = 0; jb < 2; ++jb) {
            const unsigned short* wb = jb ? wWm : wWn;
            unsigned short* dst = jb ? s_eb : s_npb;
            short8 bfr[4];
#pragma unroll
            for (int kt = 0; kt < 4; ++kt) bfr[kt] = bfrag(wb, wave, 4, kt, lane);
#pragma unroll
            for (int mt = 0; mt < 3; ++mt) {
                floatx4 acc = {0.f, 0.f, 0.f, 0.f};
#pragma unroll
                for (int kt = 0; kt < 4; ++kt) acc = mm(afrag(s_hb, mt, kt, lane), bfr[kt], acc);
#pragma unroll
                for (int reg = 0; reg < 4; ++reg) {
                    int row = mt * 16 + quad * 4 + reg;
                    if (row < Nc) dst[row * ROWP + col] = f2bf(acc[reg]);
                }
            }
        }
        __syncthreads();

        // ---- Attention (VALU, sparse, LDS edge pool) ----
        {
            float wef[FEc];
#pragma unroll
            for (int f = 0; f < FEc; ++f) wef[f] = We[f * Mc + m];
#pragma unroll 1
            for (int ib = 0; ib < 10; ++ib) {
                int i = g + ib * 4;
                int cnt = s_cnt[i], base = s_off[i];
                float pden = 0.f, pnum = 0.f;
#pragma unroll 1
                for (int kn = 0; kn < cnt; ++kn) {
                    int j = s_nbr[i][kn];
                    int slot = base + kn;
                    float ep;
                    if (slot < EPOOL) {     // wave-uniform branch
                        const unsigned int* e = (const unsigned int*)(s_pool + slot * FEc);
                        uint4 p0 = *(const uint4*)e;
                        uint4 p1 = *(const uint4*)(e + 4);
                        ep = bflo(p0.x)*wef[0]  + bfhi(p0.x)*wef[1]
                           + bflo(p0.y)*wef[2]  + bfhi(p0.y)*wef[3]
                           + bflo(p0.z)*wef[4]  + bfhi(p0.z)*wef[5]
                           + bflo(p0.w)*wef[6]  + bfhi(p0.w)*wef[7]
                           + bflo(p1.x)*wef[8]  + bfhi(p1.x)*wef[9]
                           + bflo(p1.y)*wef[10] + bfhi(p1.y)*wef[11]
                           + bflo(p1.z)*wef[12] + bfhi(p1.z)*wef[13]
                           + bflo(p1.w)*wef[14] + bfhi(p1.w)*wef[15];
                    } else {                // pool overflow fallback (statistically never)
                        const float4* ef = (const float4*)(edges_b + ((size_t)i * Nc + j) * FEc);
                        float4 a0 = ef[0], a1 = ef[1], a2 = ef[2], a3 = ef[3];
                        ep = a0.x*wef[0] + a0.y*wef[1] + a0.z*wef[2] + a0.w*wef[3]
                           + a1.x*wef[4] + a1.y*wef[5] + a1.z*wef[6] + a1.w*wef[7]
                           + a2.x*wef[8] + a2.y*wef[9] + a2.z*wef[10]+ a2.w*wef[11]
                           + a3.x*wef[12]+ a3.y*wef[13]+ a3.z*wef[14]+ a3.w*wef[15];
                    }
                    float x = ep + bf2f(s_npb[j * ROWP + m]);
                    float w = __expf(fast_tanh(x));   // logits in (-1,1): no max-sub needed
                    pden += w;
                    pnum += w * bf2f(s_eb[j * ROWP + m]);
                }
                s_mb[i * ROWP + m] = f2bf((cnt > 0) ? pnum * fast_rcp(pden) : 0.f);
            }
        }
        __syncthreads();

        // ---- GRU phase 1: r,z gates (6 accumulators live, 4 B-frags/kt) ----
        float rg[3][4], zg[3][4];
        {
            floatx4 racc[3], zacc[3];
#pragma unroll
            for (int mt = 0; mt < 3; ++mt) { racc[mt] = {0.f,0.f,0.f,0.f}; zacc[mt] = {0.f,0.f,0.f,0.f}; }
#pragma unroll
            for (int kt = 0; kt < 4; ++kt) {
                short8 bir = bfrag(wWi, wave,     4, kt, lane);
                short8 bhr = bfrag(wWh, wave,     4, kt, lane);
                short8 biz = bfrag(wWi, wave + 8, 4, kt, lane);
                short8 bhz = bfrag(wWh, wave + 8, 4, kt, lane);
#pragma unroll
                for (int mt = 0; mt < 3; ++mt) {
                    short8 am = afrag(s_mb, mt, kt, lane);
                    short8 ah = afrag(s_hb, mt, kt, lane);
                    racc[mt] = mm(am, bir, racc[mt]);  racc[mt] = mm(ah, bhr, racc[mt]);
                    zacc[mt] = mm(am, biz, zacc[mt]);  zacc[mt] = mm(ah, bhz, zacc[mt]);
                }
            }
            float br = bi[col] + bh[col];
            float bz = bi[Mc + col] + bh[Mc + col];
#pragma unroll
            for (int mt = 0; mt < 3; ++mt)
#pragma unroll
                for (int reg = 0; reg < 4; ++reg) {
                    rg[mt][reg] = fast_sigmoid(racc[mt][reg] + br);
                    zg[mt][reg] = fast_sigmoid(zacc[mt][reg] + bz);
                }
        }
        // ---- GRU phase 2: candidate n, h update (read-read on LDS, no barrier needed) ----
        float hn[3][4];
        {
            floatx4 iacc[3], hacc[3];
#pragma unroll
            for (int mt = 0; mt < 3; ++mt) { iacc[mt] = {0.f,0.f,0.f,0.f}; hacc[mt] = {0.f,0.f,0.f,0.f}; }
#pragma unroll
            for (int kt = 0; kt < 4; ++kt) {
                short8 bin8 = bfrag(wWi, wave + 16, 4, kt, lane);
                short8 bhn8 = bfrag(wWh, wave + 16, 4, kt, lane);
#pragma unroll
                for (int mt = 0; mt < 3; ++mt) {
                    iacc[mt] = mm(afrag(s_mb, mt, kt, lane), bin8, iacc[mt]);
                    hacc[mt] = mm(afrag(s_hb, mt, kt, lane), bhn8, hacc[mt]);
                }
            }
            float bnI = bi[2 * Mc + col];
            float bnH = bh[2 * Mc + col];
#pragma unroll
            for (int mt = 0; mt < 3; ++mt)
#pragma unroll
                for (int reg = 0; reg < 4; ++reg) {
                    int row = mt * 16 + quad * 4 + reg;
                    float hold = hreg[mt][reg];
                    float n = fast_tanh(iacc[mt][reg] + bnI + rg[mt][reg] * (hacc[mt][reg] + bnH));
                    float v = (1.f - zg[mt][reg]) * n + zg[mt][reg] * hold;
                    hn[mt][reg] = (row < Nc && s_cnt[row] > 0) ? v : hold;
                }
        }
        __syncthreads();   // all MFMA reads of s_hb/s_mb done before overwrite
#pragma unroll
        for (int mt = 0; mt < 3; ++mt)
#pragma unroll
            for (int reg = 0; reg < 4; ++reg) {
                int row = mt * 16 + quad * 4 + reg;
                hreg[mt][reg] = hn[mt][reg];
                if (row < Nc) s_hb[row * ROWP + col] = f2bf(hn[mt][reg]);
            }
        __syncthreads();
    }

    // ---- Readout: out = sum_i mask * sigmoid(cat@Wg+bg) * (cat@Wo+bo) ----
    for (int idx = tid; idx < Nc * Hc; idx += T) {
        int row = idx >> 7, c2 = idx & 127;
        s_mb[row * ROWP + c2] = f2bf(nodes_b[idx]);   // cat tail (messages dead)
    }
    __syncthreads();
    floatx4 gacc[3], oacc[3];
#pragma unroll
    for (int mt = 0; mt < 3; ++mt) { gacc[mt] = {0.f,0.f,0.f,0.f}; oacc[mt] = {0.f,0.f,0.f,0.f}; }
#pragma unroll
    for (int kt = 0; kt < 8; ++kt) {
        short8 bg8 = bfrag(wWg, wave, 8, kt, lane);
        short8 bo8 = bfrag(wWo, wave, 8, kt, lane);
#pragma unroll
        for (int mt = 0; mt < 3; ++mt) {
            short8 a = (kt < 4) ? afrag(s_hb, mt, kt, lane) : afrag(s_mb, mt, kt - 4, lane);
            gacc[mt] = mm(a, bg8, gacc[mt]);
            oacc[mt] = mm(a, bo8, oacc[mt]);
        }
    }
    float bgv = bg[col], bov = bo[col], psum = 0.f;
#pragma unroll
    for (int mt = 0; mt < 3; ++mt)
#pragma unroll
        for (int reg = 0; reg < 4; ++reg) {
            int row = mt * 16 + quad * 4 + reg;
            if (row < Nc && s_cnt[row] > 0)
                psum += fast_sigmoid(gacc[mt][reg] + bgv) * (oacc[mt][reg] + bov);
        }
    psum += __shfl_xor(psum, 16);   // reduce over the 4 quads sharing this col
    psum += __shfl_xor(psum, 32);
    if (quad == 0) out[(size_t)b * OUTc + col] = psum;
}

extern "C" void kernel_launch(void* const* d_in, const int* in_sizes, int n_in,
                              void* d_out, int out_size, void* d_ws, size_t ws_size,
                              hipStream_t stream) {
    const float* nodes = (const float*)d_in[0];
    const float* edges = (const float*)d_in[1];
    const float* We = (const float*)d_in[2];
    const float* Wn = (const float*)d_in[3];
    const float* Wm = (const float*)d_in[4];
    const float* Wi = (const float*)d_in[5];
    const float* Wh = (const float*)d_in[6];
    const float* bi = (const float*)d_in[7];
    const float* bh = (const float*)d_in[8];
    const float* Wg = (const float*)d_in[9];
    const float* bg = (const float*)d_in[10];
    const float* Wo = (const float*)d_in[11];
    const float* bo = (const float*)d_in[12];
    float* out = (float*)d_out;
    unsigned short* ws = (unsigned short*)d_ws;

    prep_kernel<<<384, 64, 0, stream>>>(Wn, Wm, Wi, Wh, Wg, Wo, ws);
    mpnn_kernel<<<Bc, T, 0, stream>>>(nodes, edges, We, bi, bh, bg, bo, ws, out);
}

// Round 6
// 366.913 us; speedup vs baseline: 1.0131x; 1.0131x over previous
//
#include <hip/hip_runtime.h>

#define T 1024
constexpr int Bc = 512, Nc = 40, Hc = 128, FEc = 16, Mc = 128, OUTc = 128, NPASS = 3;
constexpr int ROWP = 136;   // bf16 LDS row pitch
constexpr int HP   = 132;   // fp32 LDS row pitch
constexpr int EPOOL = 512;  // edge pool slots (mean ~296, sigma ~22 -> ~10 sigma headroom; fallback covers overflow)

typedef __attribute__((ext_vector_type(8))) short short8;
typedef __attribute__((ext_vector_type(4))) float floatx4;
typedef __attribute__((ext_vector_type(4))) float fvec4;

// ws layout (bf16 elements): fragment-major B operands, then K-padded We, then per-block ep
constexpr int WS_WN = 0, WS_WM = 16384, WS_WI = 32768, WS_WH = 81920, WS_WG = 131072, WS_WO = 163840;
constexpr int WS_WE16 = 196608;           // We padded to K=32 (8 frag tiles)
constexpr int WS_EP   = 200704;           // ep: Bc * EPOOL * 128 bf16

__device__ __forceinline__ float fast_rcp(float x) { return __builtin_amdgcn_rcpf(x); }
__device__ __forceinline__ float fast_sigmoid(float x) { return fast_rcp(1.f + __expf(-x)); }
__device__ __forceinline__ float fast_tanh(float x) {
    float t = __expf(2.f * x);
    return 1.f - 2.f * fast_rcp(t + 1.f);
}
__device__ __forceinline__ float bf2f(unsigned short u) {
    union { unsigned int i; float f; } v; v.i = ((unsigned int)u) << 16; return v.f;
}
__device__ __forceinline__ unsigned short f2bf(float f) {
    union { float f; unsigned int i; } v; v.f = f;
    unsigned int r = v.i + 0x7fff + ((v.i >> 16) & 1);   // RNE
    return (unsigned short)(r >> 16);
}
__device__ __forceinline__ float bflo(unsigned int d) {
    union { unsigned int i; float f; } v; v.i = d << 16; return v.f;
}
__device__ __forceinline__ float bfhi(unsigned int d) {
    union { unsigned int i; float f; } v; v.i = d & 0xffff0000u; return v.f;
}

__device__ __forceinline__ floatx4 mm(short8 a, short8 b, floatx4 c) {
    return __builtin_amdgcn_mfma_f32_16x16x32_bf16(a, b, c, 0, 0, 0);
}
// A-fragment from LDS bf16 buffer: A[m=lane&15][k=quad*8+j]; rows>=40 clamped (their C rows discarded)
__device__ __forceinline__ short8 afrag(const unsigned short* buf, int mt, int kt, int lane) {
    int row = mt * 16 + (lane & 15); row = row > 39 ? 39 : row;
    return *(const short8*)(buf + row * ROWP + kt * 32 + (lane >> 4) * 8);
}
// B-fragment from global frag buffer (L2-resident)
__device__ __forceinline__ short8 bfrag(const unsigned short* w, int nt, int nKT, int kt, int lane) {
    return *(const short8*)(w + ((nt * nKT + kt) * 64 + lane) * 8);
}

// ---- prep: weights -> bf16 B-fragment layout in ws ----
__global__ void prep_kernel(const float* __restrict__ Wn, const float* __restrict__ Wm,
                            const float* __restrict__ Wi, const float* __restrict__ Wh,
                            const float* __restrict__ Wg, const float* __restrict__ Wo,
                            const float* __restrict__ We, unsigned short* __restrict__ ws) {
    int c = blockIdx.x, lane = threadIdx.x;
    int quad = lane >> 4, l16 = lane & 15;
    if (c >= 384) {          // We padded to K=32 (rows 16..31 zero)
        int nt = c - 384;
        short8 v;
#pragma unroll
        for (int j = 0; j < 8; ++j) {
            int k = quad * 8 + j;
            v[j] = (k < FEc) ? (short)f2bf(We[k * Mc + nt * 16 + l16]) : (short)0;
        }
        *(short8*)(ws + WS_WE16 + nt * 512 + lane * 8) = v;
        return;
    }
    const float* W; int N, nKT, local; unsigned short* dst;
    if (c < 32)       { W = Wn; N = 128; nKT = 4; local = c;       dst = ws + WS_WN; }
    else if (c < 64)  { W = Wm; N = 128; nKT = 4; local = c - 32;  dst = ws + WS_WM; }
    else if (c < 160) { W = Wi; N = 384; nKT = 4; local = c - 64;  dst = ws + WS_WI; }
    else if (c < 256) { W = Wh; N = 384; nKT = 4; local = c - 160; dst = ws + WS_WH; }
    else if (c < 320) { W = Wg; N = 128; nKT = 8; local = c - 256; dst = ws + WS_WG; }
    else              { W = Wo; N = 128; nKT = 8; local = c - 320; dst = ws + WS_WO; }
    int nt = local / nKT, kt = local % nKT;
    short8 v;
#pragma unroll
    for (int j = 0; j < 8; ++j) {
        int k = kt * 32 + quad * 8 + j;
        v[j] = (short)f2bf(W[k * N + nt * 16 + l16]);
    }
    *(short8*)(dst + local * 512 + lane * 8) = v;
}

// T=1024: 16 waves, 1 block/CU (LDS ~104 KB). One MFMA tile per wave-task at a time
// keeps arch-reg live set ~55 (fits the compiler's even V/A split at budget 128).
__global__ __launch_bounds__(T, 4) void mpnn_kernel(
    const float* __restrict__ nodes, const float* __restrict__ edges,
    const float* __restrict__ We, const float* __restrict__ bi,
    const float* __restrict__ bh, const float* __restrict__ bg,
    const float* __restrict__ bo, const unsigned short* __restrict__ ws,
    unsigned short* __restrict__ ep_g,   // null if ws too small
    float* __restrict__ out)
{
    __shared__ __attribute__((aligned(16))) unsigned short s_hb[Nc * ROWP];   // bf16 h
    __shared__ __attribute__((aligned(16))) unsigned short s_mb[Nc * ROWP];   // bf16 messages / nodes(cat)
    __shared__ __attribute__((aligned(16))) unsigned short s_npb[Nc * ROWP];  // np, then r-gate; init: slot_src tmp
    __shared__ __attribute__((aligned(16))) unsigned short s_eb[Nc * ROWP];   // emb, then z-gate
    __shared__ float s_hf[Nc * HP];                                           // fp32 h
    __shared__ float s_nf[Nc * HP];                                           // fp32 h_new staging
    __shared__ __attribute__((aligned(16))) unsigned short s_pool[EPOOL * FEc]; // 16 KB edge features
    __shared__ unsigned char s_nbr[Nc][Nc];
    __shared__ int s_cnt[Nc];
    __shared__ int s_off[Nc];
    __shared__ int s_total;
    __shared__ float s_out[OUTc];

    const int b = blockIdx.x, tid = threadIdx.x;
    const int lane = tid & 63, wave = tid >> 6;          // 16 waves
    const int quad = lane >> 4, l16 = lane & 15;
    const int m = tid & 127, g = tid >> 7;               // attention: g in 0..7

    const float* nodes_b = nodes + (size_t)b * Nc * Hc;
    const float* edges_b = edges + (size_t)b * Nc * Nc * FEc;
    const unsigned short* wWn = ws + WS_WN; const unsigned short* wWm = ws + WS_WM;
    const unsigned short* wWi = ws + WS_WI; const unsigned short* wWh = ws + WS_WH;
    const unsigned short* wWg = ws + WS_WG; const unsigned short* wWo = ws + WS_WO;
    const unsigned short* wWe16 = ws + WS_WE16;
    unsigned short* epb = ep_g ? ep_g + (size_t)b * EPOOL * Mc : nullptr;

    // ---- init h (fp32 + bf16, both LDS) ----
    for (int idx = tid; idx < Nc * Hc; idx += T) {
        int row = idx >> 7, c2 = idx & 127;
        float v = nodes_b[idx];
        s_hf[row * HP + c2] = v;
        s_hb[row * ROWP + c2] = f2bf(v);
    }
    // ---- adjacency scan (streaming, non-temporal) ----
    for (int p = tid; p < Nc * Nc; p += T) {
        const fvec4* e4 = (const fvec4*)(edges_b + p * FEc);
        fvec4 a0 = __builtin_nontemporal_load(e4);
        fvec4 a1 = __builtin_nontemporal_load(e4 + 1);
        fvec4 a2 = __builtin_nontemporal_load(e4 + 2);
        fvec4 a3 = __builtin_nontemporal_load(e4 + 3);
        float s = a0.x + a0.y + a0.z + a0.w + a1.x + a1.y + a1.z + a1.w
                + a2.x + a2.y + a2.z + a2.w + a3.x + a3.y + a3.z + a3.w;
        ((unsigned char*)s_nbr)[p] = (s > 0.f) ? 1 : 0;
    }
    __syncthreads();
    if (tid < Nc) {               // compact neighbor list in place
        int c = 0;
#pragma unroll 1
        for (int j = 0; j < Nc; ++j)
            if (s_nbr[tid][j]) { s_nbr[tid][c] = (unsigned char)j; ++c; }
        s_cnt[tid] = c;
    }
    __syncthreads();
    if (tid == 0) {
        int tot = 0;
#pragma unroll 1
        for (int i = 0; i < Nc; ++i) { s_off[i] = tot; tot += s_cnt[i]; }
        s_total = tot;
    }
    __syncthreads();
    int* slot_src = (int*)s_npb;  // temp alias
    if (tid < Nc) {
        int base = s_off[tid], cnt = s_cnt[tid];
#pragma unroll 1
        for (int kn = 0; kn < cnt; ++kn) {
            int slot = base + kn;
            if (slot < EPOOL) slot_src[slot] = tid * Nc + s_nbr[tid][kn];
        }
    }
    __syncthreads();
    const int E = s_total < EPOOL ? s_total : EPOOL;
    {   // fill compact bf16 edge pool; zero the tail (clean MFMA inputs)
#pragma unroll 1
        for (int w = tid; w < EPOOL * 2; w += T) {
            int s = w >> 1, hf = w & 1;
            short8 v = {0,0,0,0,0,0,0,0};
            if (s < E) {
                const float* src = edges_b + (size_t)slot_src[s] * FEc + hf * 8;
                fvec4 x = __builtin_nontemporal_load((const fvec4*)src);
                fvec4 y = __builtin_nontemporal_load((const fvec4*)(src + 4));
                v[0] = (short)f2bf(x.x); v[1] = (short)f2bf(x.y); v[2] = (short)f2bf(x.z); v[3] = (short)f2bf(x.w);
                v[4] = (short)f2bf(y.x); v[5] = (short)f2bf(y.y); v[6] = (short)f2bf(y.z); v[7] = (short)f2bf(y.w);
            }
            *(short8*)(s_pool + s * FEc + hf * 8) = v;
        }
    }
    __syncthreads();

    // ---- ep = edges@We via MFMA, once per block (pass-invariant), to global ws ----
    if (epb) {
        int nT = (E + 15) >> 4;
#pragma unroll 1
        for (int st = wave; st < nT; st += 16) {
            short8 a = {0,0,0,0,0,0,0,0};
            if (quad < 2)   // K=quad*8+j < 16 from pool; upper K zero (We rows padded)
                a = *(const short8*)(s_pool + (st * 16 + l16) * FEc + quad * 8);
#pragma unroll
            for (int nt = 0; nt < 8; ++nt) {
                floatx4 acc = {0.f, 0.f, 0.f, 0.f};
                acc = mm(a, bfrag(wWe16, nt, 1, 0, lane), acc);
#pragma unroll
                for (int reg = 0; reg < 4; ++reg) {
                    int slot = st * 16 + quad * 4 + reg;
                    if (slot < EPOOL) epb[slot * Mc + nt * 16 + l16] = f2bf(acc[reg]);
                }
            }
        }
    }
    __syncthreads();   // also orders global ep writes vs reads within block

    for (int pass = 0; pass < NPASS; ++pass) {
        // ---- Phase A: np = h@Wn, emb = h@Wm. 16 waves <-> 16 (jb,nt) tiles ----
        {
            int jb = wave >> 3, nt = wave & 7;
            const unsigned short* wb = jb ? wWm : wWn;
            unsigned short* dst = jb ? s_eb : s_npb;
            short8 bfr[4];
#pragma unroll
            for (int kt = 0; kt < 4; ++kt) bfr[kt] = bfrag(wb, nt, 4, kt, lane);
#pragma unroll
            for (int mt = 0; mt < 3; ++mt) {
                floatx4 acc = {0.f, 0.f, 0.f, 0.f};
#pragma unroll
                for (int kt = 0; kt < 4; ++kt) acc = mm(afrag(s_hb, mt, kt, lane), bfr[kt], acc);
#pragma unroll
                for (int reg = 0; reg < 4; ++reg) {
                    int row = mt * 16 + quad * 4 + reg;
                    if (row < Nc) dst[row * ROWP + nt * 16 + l16] = f2bf(acc[reg]);
                }
            }
        }
        __syncthreads();

        // ---- Attention: 8 row-groups x 5 rows; inner loop ~18 VALU with precomputed ep ----
#pragma unroll 1
        for (int ib = 0; ib < 5; ++ib) {
            int i = g + ib * 8;
            int cnt = s_cnt[i], base = s_off[i];
            float pden = 0.f, pnum = 0.f;
            if (epb) {
#pragma unroll 1
                for (int kn = 0; kn < cnt; ++kn) {
                    int j = s_nbr[i][kn];
                    int slot = base + kn;
                    float ep;
                    if (slot < EPOOL) ep = bf2f(epb[slot * Mc + m]);
                    else {             // overflow fallback (statistically never)
                        const float4* ef = (const float4*)(edges_b + ((size_t)i * Nc + j) * FEc);
                        float4 a0 = ef[0], a1 = ef[1], a2 = ef[2], a3 = ef[3];
                        ep = a0.x*We[0*Mc+m] + a0.y*We[1*Mc+m] + a0.z*We[2*Mc+m] + a0.w*We[3*Mc+m]
                           + a1.x*We[4*Mc+m] + a1.y*We[5*Mc+m] + a1.z*We[6*Mc+m] + a1.w*We[7*Mc+m]
                           + a2.x*We[8*Mc+m] + a2.y*We[9*Mc+m] + a2.z*We[10*Mc+m]+ a2.w*We[11*Mc+m]
                           + a3.x*We[12*Mc+m]+ a3.y*We[13*Mc+m]+ a3.z*We[14*Mc+m]+ a3.w*We[15*Mc+m];
                    }
                    float x = ep + bf2f(s_npb[j * ROWP + m]);
                    float w = __expf(fast_tanh(x));   // logits in (-1,1): no max-sub needed
                    pden += w;
                    pnum += w * bf2f(s_eb[j * ROWP + m]);
                }
            } else {   // no-ws fallback: bf16 pool dot product
                float wef[FEc];
#pragma unroll
                for (int f = 0; f < FEc; ++f) wef[f] = We[f * Mc + m];
#pragma unroll 1
                for (int kn = 0; kn < cnt; ++kn) {
                    int j = s_nbr[i][kn];
                    int slot = base + kn;
                    float ep;
                    if (slot < EPOOL) {
                        const unsigned int* e = (const unsigned int*)(s_pool + slot * FEc);
                        uint4 p0 = *(const uint4*)e;
                        uint4 p1 = *(const uint4*)(e + 4);
                        ep = bflo(p0.x)*wef[0]  + bfhi(p0.x)*wef[1]
                           + bflo(p0.y)*wef[2]  + bfhi(p0.y)*wef[3]
                           + bflo(p0.z)*wef[4]  + bfhi(p0.z)*wef[5]
                           + bflo(p0.w)*wef[6]  + bfhi(p0.w)*wef[7]
                           + bflo(p1.x)*wef[8]  + bfhi(p1.x)*wef[9]
                           + bflo(p1.y)*wef[10] + bfhi(p1.y)*wef[11]
                           + bflo(p1.z)*wef[12] + bfhi(p1.z)*wef[13]
                           + bflo(p1.w)*wef[14] + bfhi(p1.w)*wef[15];
                    } else {
                        const float4* ef = (const float4*)(edges_b + ((size_t)i * Nc + j) * FEc);
                        float4 a0 = ef[0], a1 = ef[1], a2 = ef[2], a3 = ef[3];
                        ep = a0.x*wef[0] + a0.y*wef[1] + a0.z*wef[2] + a0.w*wef[3]
                           + a1.x*wef[4] + a1.y*wef[5] + a1.z*wef[6] + a1.w*wef[7]
                           + a2.x*wef[8] + a2.y*wef[9] + a2.z*wef[10]+ a2.w*wef[11]
                           + a3.x*wef[12]+ a3.y*wef[13]+ a3.z*wef[14]+ a3.w*wef[15];
                    }
                    float x = ep + bf2f(s_npb[j * ROWP + m]);
                    float w = __expf(fast_tanh(x));
                    pden += w;
                    pnum += w * bf2f(s_eb[j * ROWP + m]);
                }
            }
            s_mb[i * ROWP + m] = f2bf((cnt > 0) ? pnum * fast_rcp(pden) : 0.f);
        }
        __syncthreads();

        // ---- GRU alpha: r,z gates. 48 tiles (grp{0,1} x 8 nt x 3 mt), 3 per wave ----
#pragma unroll 1
        for (int t = wave; t < 48; t += 16) {
            int grp = t / 24, rem = t % 24, nt = rem & 7, mt = rem >> 3;
            floatx4 a1 = {0.f,0.f,0.f,0.f}, a2 = {0.f,0.f,0.f,0.f};
#pragma unroll
            for (int kt = 0; kt < 4; ++kt) {
                a1 = mm(afrag(s_mb, mt, kt, lane), bfrag(wWi, grp * 8 + nt, 4, kt, lane), a1);
                a2 = mm(afrag(s_hb, mt, kt, lane), bfrag(wWh, grp * 8 + nt, 4, kt, lane), a2);
            }
            int cl = nt * 16 + l16;
            float bb = bi[grp * 128 + cl] + bh[grp * 128 + cl];
            unsigned short* dst = grp ? s_eb : s_npb;   // np/emb dead after attention
#pragma unroll
            for (int reg = 0; reg < 4; ++reg) {
                int row = mt * 16 + quad * 4 + reg;
                if (row < Nc) dst[row * ROWP + cl] = f2bf(fast_sigmoid(a1[reg] + a2[reg] + bb));
            }
        }
        __syncthreads();

        // ---- GRU beta: candidate n + h update -> fp32 staging. 24 tiles ----
#pragma unroll 1
        for (int t = wave; t < 24; t += 16) {
            int nt = t & 7, mt = t >> 3;
            floatx4 ai = {0.f,0.f,0.f,0.f}, ah = {0.f,0.f,0.f,0.f};
#pragma unroll
            for (int kt = 0; kt < 4; ++kt) {
                ai = mm(afrag(s_mb, mt, kt, lane), bfrag(wWi, 16 + nt, 4, kt, lane), ai);
                ah = mm(afrag(s_hb, mt, kt, lane), bfrag(wWh, 16 + nt, 4, kt, lane), ah);
            }
            int cl = nt * 16 + l16;
            float bnI = bi[256 + cl], bnH = bh[256 + cl];
#pragma unroll
            for (int reg = 0; reg < 4; ++reg) {
                int row = mt * 16 + quad * 4 + reg;
                if (row < Nc) {
                    float r = bf2f(s_npb[row * ROWP + cl]);
                    float z = bf2f(s_eb[row * ROWP + cl]);
                    float hold = s_hf[row * HP + cl];
                    float n = fast_tanh(ai[reg] + bnI + r * (ah[reg] + bnH));
                    float v = (1.f - z) * n + z * hold;
                    s_nf[row * HP + cl] = (s_cnt[row] > 0) ? v : hold;
                }
            }
        }
        __syncthreads();
        // ---- commit h ----
        for (int idx = tid; idx < Nc * Hc; idx += T) {
            int row = idx >> 7, c2 = idx & 127;
            float v = s_nf[row * HP + c2];
            s_hf[row * HP + c2] = v;
            s_hb[row * ROWP + c2] = f2bf(v);
        }
        __syncthreads();
    }

    // ---- Readout: out = sum_i mask * sigmoid(cat@Wg+bg) * (cat@Wo+bo) ----
    for (int idx = tid; idx < Nc * Hc; idx += T) {
        int row = idx >> 7, c2 = idx & 127;
        s_mb[row * ROWP + c2] = f2bf(nodes_b[idx]);   // cat tail (messages dead)
    }
    if (tid < OUTc) s_out[tid] = 0.f;
    __syncthreads();
#pragma unroll 1
    for (int t = wave; t < 24; t += 16) {
        int nt = t & 7, mt = t >> 3;
        floatx4 ga = {0.f,0.f,0.f,0.f}, oa = {0.f,0.f,0.f,0.f};
#pragma unroll
        for (int kt = 0; kt < 8; ++kt) {
            short8 a = (kt < 4) ? afrag(s_hb, mt, kt, lane) : afrag(s_mb, mt, kt - 4, lane);
            ga = mm(a, bfrag(wWg, nt, 8, kt, lane), ga);
            oa = mm(a, bfrag(wWo, nt, 8, kt, lane), oa);
        }
        int cl = nt * 16 + l16;
        float bgv = bg[cl], bov = bo[cl], part = 0.f;
#pragma unroll
        for (int reg = 0; reg < 4; ++reg) {
            int row = mt * 16 + quad * 4 + reg;
            if (row < Nc && s_cnt[row] > 0)
                part += fast_sigmoid(ga[reg] + bgv) * (oa[reg] + bov);
        }
        part += __shfl_xor(part, 16);
        part += __shfl_xor(part, 32);
        if (quad == 0) atomicAdd(&s_out[cl], part);
    }
    __syncthreads();
    if (tid < OUTc) out[(size_t)b * OUTc + tid] = s_out[tid];
}

extern "C" void kernel_launch(void* const* d_in, const int* in_sizes, int n_in,
                              void* d_out, int out_size, void* d_ws, size_t ws_size,
                              hipStream_t stream) {
    const float* nodes = (const float*)d_in[0];
    const float* edges = (const float*)d_in[1];
    const float* We = (const float*)d_in[2];
    const float* Wn = (const float*)d_in[3];
    const float* Wm = (const float*)d_in[4];
    const float* Wi = (const float*)d_in[5];
    const float* Wh = (const float*)d_in[6];
    const float* bi = (const float*)d_in[7];
    const float* bh = (const float*)d_in[8];
    const float* Wg = (const float*)d_in[9];
    const float* bg = (const float*)d_in[10];
    const float* Wo = (const float*)d_in[11];
    const float* bo = (const float*)d_in[12];
    float* out = (float*)d_out;
    unsigned short* ws = (unsigned short*)d_ws;

    size_t need = ((size_t)WS_EP + (size_t)Bc * EPOOL * Mc) * sizeof(unsigned short);
    unsigned short* ep_g = (ws_size >= need) ? ws + WS_EP : nullptr;

    prep_kernel<<<392, 64, 0, stream>>>(Wn, Wm, Wi, Wh, Wg, Wo, We, ws);
    mpnn_kernel<<<Bc, T, 0, stream>>>(nodes, edges, We, bi, bh, bg, bo, ws, ep_g, out);
}